// Round 12
// baseline (127.357 us; speedup 1.0000x reference)
//
#include <hip/hip_runtime.h>

#define HH 480
#define WW 640
#define BB 4
#define PPP 4
#define NN 262144
#define HWPX (HH * WW)

// scatter tiling: 24x80 tiles, 20 rows x 8 cols per batch
#define TH 24
#define TW 80
#define TXN 8                // tiles per row
#define TYN 20               // tiles per col
#define TPB 160              // tiles per batch (20x8)
#define NT (BB * TPB)        // 640 tiles total
#define CAP 2048             // bucket capacity (mean ~1728 incl dups, >7 sigma)
#define CAPSHIFT 11

#define NTEMP 1800           // temporal units: 12 pairs x 150
#define NSPAT 2400           // spatial units: 16 planes x 150
#define NBIN 1024            // bin blocks

__device__ __forceinline__ float charb6(float a) { return sqrtf(a * a + 1e-6f); }

// ---------------- block reduce helper (256 threads) ----------------
__device__ __forceinline__ float block_reduce_256(float v, float* smem) {
#pragma unroll
    for (int off = 32; off > 0; off >>= 1) v += __shfl_down(v, off, 64);
    int lane = threadIdx.x & 63;
    int wid = threadIdx.x >> 6;
    if (lane == 0) smem[wid] = v;
    __syncthreads();
    float r = 0.0f;
    if (threadIdx.x == 0) r = smem[0] + smem[1] + smem[2] + smem[3];
    __syncthreads();
    return r;  // valid only on thread 0
}

// ---------------- Spatial work unit: 2048 px of one plane ----------------
__device__ void spat_work(int s, const float* __restrict__ flow,
                          float* __restrict__ acc, float* smem) {
    int tid = threadIdx.x;
    int plane = s / 150;
    int rem = s - plane * 150;

    const float* fx = flow + (size_t)(plane * 2) * HWPX;
    const float* fy = fx + HWPX;

    const float wdx = 1.0f / ((float)HH * (float)(WW - 1) * (float)PPP * 4.0f);
    const float wdy = 1.0f / ((float)(HH - 1) * (float)WW * (float)PPP * 4.0f);
    const float wdd = 1.0f / ((float)(HH - 1) * (float)(WW - 1) * (float)PPP * 4.0f);

    float a_sp = 0.0f;

#pragma unroll
    for (int q = 0; q < 2; ++q) {
        int off = rem * 2048 + q * 1024 + tid * 4;
        int h = off / WW;
        int c = off - h * WW;

        float mhe = (h < HH - 1) ? 1.0f : 0.0f;
        int ib = (h < HH - 1) ? off + WW : off;
        int ir = (c + 4 < WW) ? off + 4 : off + 3;
        int ibr = (c + 4 < WW) ? ib + 4 : ib + 3;

        float4 fxv = *(const float4*)(fx + off);
        float4 fyv = *(const float4*)(fy + off);
        float4 fxb = *(const float4*)(fx + ib);
        float4 fyb = *(const float4*)(fy + ib);
        float X[5] = {fxv.x, fxv.y, fxv.z, fxv.w, fx[ir]};
        float Y[5] = {fyv.x, fyv.y, fyv.z, fyv.w, fy[ir]};
        float XB[5] = {fxb.x, fxb.y, fxb.z, fxb.w, fx[ibr]};
        float YB[5] = {fyb.x, fyb.y, fyb.z, fyb.w, fy[ibr]};

#pragma unroll
        for (int k = 0; k < 4; ++k) {
            float mwe = (c + k < WW - 1) ? 1.0f : 0.0f;
            a_sp += mwe * wdx * (charb6(X[k] - X[k + 1]) + charb6(Y[k] - Y[k + 1]))
                  + mhe * wdy * (charb6(X[k] - XB[k]) + charb6(Y[k] - YB[k]))
                  + mhe * mwe * wdd * (charb6(X[k] - XB[k + 1]) + charb6(Y[k] - YB[k + 1])
                                     + charb6(XB[k] - X[k + 1]) + charb6(YB[k] - Y[k + 1]));
        }
    }

    float r_sp = block_reduce_256(a_sp, smem);
    if (tid == 0) atomicAdd(&acc[4 + plane], r_sp);
}

// ---------------- Temporal work unit: 2048 px of one plane-pair -----------
__device__ void temp_work(int u, const float* __restrict__ flow,
                          float* __restrict__ acc, float* smem) {
    int tid = threadIdx.x;
    int pair = u / 150;        // 0..11
    int rem = u - pair * 150;
    int bb = pair / 3, pp = pair - bb * 3;
    int cp = bb * 4 + pp;      // cur plane id
    const float* fxc = flow + (size_t)(cp * 2) * HWPX;
    const float* fyc = fxc + HWPX;
    const float* fxn = fxc + 2 * HWPX;
    const float* fyn = fyc + 2 * HWPX;

    float a_dt = 0.0f, a_m = 0.0f;

#pragma unroll
    for (int q = 0; q < 2; ++q) {
        int off = rem * 2048 + q * 1024 + tid * 4;
        int h = off / WW;
        int c = off - h * WW;

        float4 xv = *(const float4*)(fxc + off);
        float4 yv = *(const float4*)(fyc + off);
        float X[4] = {xv.x, xv.y, xv.z, xv.w};
        float Y[4] = {yv.x, yv.y, yv.z, yv.w};

        float msk[4], w00[4], w01[4], w10[4], w11[4];
        int aA[4], aB[4], sel[4];
#pragma unroll
        for (int k = 0; k < 4; ++k) {
            float wy = (float)h + Y[k];
            float wx = (float)(c + k) + X[k];
            msk[k] = (wy >= 0.0f && wy <= (float)(HH - 1) &&
                      wx >= 0.0f && wx <= (float)(WW - 1)) ? 1.0f : 0.0f;
            float y0f = floorf(wy), x0f = floorf(wx);
            float fy1 = wy - y0f, fx1 = wx - x0f;
            float fy0 = 1.0f - fy1, fx0 = 1.0f - fx1;
            w00[k] = fy0 * fx0; w01[k] = fy0 * fx1;
            w10[k] = fy1 * fx0; w11[k] = fy1 * fx1;
            int y0 = (int)fminf(fmaxf(y0f, 0.0f), (float)(HH - 1));
            int y1 = (int)fminf(fmaxf(y0f + 1.0f, 0.0f), (float)(HH - 1));
            int x0 = (int)fminf(fmaxf(x0f, 0.0f), (float)(WW - 1));
            int xl = min(x0, WW - 2);
            sel[k] = x0 - xl;
            aA[k] = y0 * WW + xl;
            aB[k] = y1 * WW + xl;
        }
        float2 A[4], B[4], C[4], D[4];
#pragma unroll
        for (int k = 0; k < 4; ++k) {
            __builtin_memcpy(&A[k], fyn + aA[k], 8);
            __builtin_memcpy(&B[k], fyn + aB[k], 8);
        }
#pragma unroll
        for (int k = 0; k < 4; ++k) {
            __builtin_memcpy(&C[k], fxn + aA[k], 8);
            __builtin_memcpy(&D[k], fxn + aB[k], 8);
        }
#pragma unroll
        for (int k = 0; k < 4; ++k) {
            float a0 = sel[k] ? A[k].y : A[k].x;
            float b0 = sel[k] ? B[k].y : B[k].x;
            float c0 = sel[k] ? C[k].y : C[k].x;
            float d0 = sel[k] ? D[k].y : D[k].x;
            float wfy = w00[k] * a0 + w01[k] * A[k].y + w10[k] * b0 + w11[k] * B[k].y;
            float wfx = w00[k] * c0 + w01[k] * C[k].y + w10[k] * d0 + w11[k] * D[k].y;
            float dy = Y[k] - wfy, dx = X[k] - wfx;
            a_dt += msk[k] * (sqrtf(dy * dy + 1e-9f) + sqrtf(dx * dx + 1e-9f));
            a_m += msk[k];
        }
    }

    float r_dt = block_reduce_256(a_dt, smem);
    float r_m = block_reduce_256(a_m, smem);
    if (tid == 0) {
        atomicAdd(&acc[20 + pair], r_dt);
        atomicAdd(&acc[52 + pair], r_m);
    }
}

// ---------------- K_A: temp || spat || bin (all independent) ---------------
// Bucket record (8B): w0 = r(5) | c<<5(7) | plane<<12(1) | qwy<<13(12)
//                     w1 = qwx(16) | qa<<16(16)
// r = ly+1 in [0,24], c = lx+1 in [0,80] (0 means "from up/left neighbor").
// Boundary-crossing events get DUPLICATE records in neighbor tiles (direct
// global-atomic slot reservation, ~5.5% of events) so every tile is final.
__global__ __launch_bounds__(256, 8) void ka_kernel(
        const float* __restrict__ ev, const float* __restrict__ pol,
        const float* __restrict__ ts, uint2* __restrict__ bucket,
        unsigned* __restrict__ gcnt, const float* __restrict__ flow,
        float* __restrict__ acc) {
    __shared__ unsigned ubuf[2 * TPB];
    __shared__ float smem[4];
    int tid = threadIdx.x;

    if (blockIdx.x < NTEMP) {
        int i = blockIdx.x;
        int u = (i & 7) * (NTEMP / 8) + (i >> 3);     // XCD-chunked, bijective
        temp_work(u, flow, acc, smem);
    } else if (blockIdx.x < NTEMP + NSPAT) {
        int i = blockIdx.x - NTEMP;
        int s = (i & 7) * (NSPAT / 8) + (i >> 3);
        spat_work(s, flow, acc, smem);
    } else {
        // ---- bin: counting-sort events into per-tile buckets ----
        unsigned* hist = ubuf;
        unsigned* basebuf = ubuf + TPB;
        if (tid < TPB) hist[tid] = 0;
        __syncthreads();

        int start = (blockIdx.x - (NTEMP + NSPAT)) * 1024;
        int b = start >> 18;
        const float2* ev2 = (const float2*)ev;

        unsigned p0[4], p1[4];
        int tt[4];
        unsigned rr[4];
        unsigned dupm[4];  // bit0: right, bit1: down
#pragma unroll
        for (int k = 0; k < 4; ++k) {
            int gidx = start + tid + k * 256;
            int n = gidx & (NN - 1);
            float2 e = ev2[gidx];
            float y = e.x, x = e.y;
            int iy = (int)floorf(y), ix = (int)floorf(x);
            int ty = iy / TH, txx = ix / TW;
            int t = ty * TXN + txx;
            int ly = iy - ty * TH, lx = ix - txx * TW;
            float wy1 = y - (float)iy, wx1 = x - (float)ix;
            float pm0 = pol[((size_t)b * 4 * NN + n) * 2];
            float tsv = ts[(size_t)b * 4 * NN + n];
            float nt = 1.0f - fabsf(1.0f - tsv);
            float a = nt * nt;
            unsigned qwy = (unsigned)(wy1 * 4095.0f + 0.5f);
            unsigned qwx = (unsigned)(wx1 * 65535.0f + 0.5f);
            unsigned qa  = (unsigned)(a * 65535.0f + 0.5f);
            unsigned plane = (pm0 > 0.5f) ? 0u : 1u;
            p0[k] = (unsigned)(ly + 1) | ((unsigned)(lx + 1) << 5) | (plane << 12) | (qwy << 13);
            p1[k] = qwx | (qa << 16);
            tt[k] = t;
            dupm[k] = ((lx == TW - 1 && txx < TXN - 1) ? 1u : 0u) |
                      ((ly == TH - 1 && ty < TYN - 1) ? 2u : 0u);
            rr[k] = atomicAdd(&hist[t], 1u);
        }
        __syncthreads();
        if (tid < TPB) basebuf[tid] = atomicAdd(&gcnt[b * TPB + tid], hist[tid]);
        __syncthreads();

#pragma unroll
        for (int k = 0; k < 4; ++k) {
            unsigned slot = basebuf[tt[k]] + rr[k];
            if (slot < CAP)
                bucket[((size_t)(b * TPB + tt[k]) << CAPSHIFT) + slot] =
                    make_uint2(p0[k], p1[k]);
            // duplicates: direct global reservation (rare)
            if (dupm[k]) {
                unsigned base0 = p0[k] & 0xFFFFE000u;  // plane|qwy bits
                unsigned r5 = p0[k] & 31u;
                unsigned c7 = (p0[k] >> 5) & 127u;
                if (dupm[k] & 1u) {  // right neighbor: c -> 0
                    int dst = b * TPB + tt[k] + 1;
                    unsigned s2 = atomicAdd(&gcnt[dst], 1u);
                    if (s2 < CAP)
                        bucket[((size_t)dst << CAPSHIFT) + s2] =
                            make_uint2(base0 | r5, p1[k]);
                }
                if (dupm[k] & 2u) {  // down neighbor: r -> 0
                    int dst = b * TPB + tt[k] + TXN;
                    unsigned s2 = atomicAdd(&gcnt[dst], 1u);
                    if (s2 < CAP)
                        bucket[((size_t)dst << CAPSHIFT) + s2] =
                            make_uint2(base0 | (c7 << 5), p1[k]);
                }
                if (dupm[k] == 3u) {  // diag neighbor: r,c -> 0
                    int dst = b * TPB + tt[k] + TXN + 1;
                    unsigned s2 = atomicAdd(&gcnt[dst], 1u);
                    if (s2 < CAP)
                        bucket[((size_t)dst << CAPSHIFT) + s2] =
                            make_uint2(base0, p1[k]);
                }
            }
        }
    }
}

// ---------------- K_B: tile accumulate + full in-tile focus + finalize -----
__global__ __launch_bounds__(256, 4) void kb_kernel(
        const uint2* __restrict__ bucket, const unsigned* __restrict__ gcnt,
        float* __restrict__ acc, unsigned* __restrict__ ticket,
        float* __restrict__ out) {
    __shared__ float S[2][TH + 2][TW + 2];   // +1 ring on all sides
    __shared__ float smem[4];
    __shared__ unsigned is_last;
    int tid = threadIdx.x;
    int l = blockIdx.x;
    int b = l / TPB;

    for (int i = tid; i < 2 * (TH + 2) * (TW + 2); i += 256) ((float*)S)[i] = 0.0f;
    __syncthreads();

    unsigned cnt = gcnt[l];
    if (cnt > CAP) cnt = CAP;
    const uint2* bk = bucket + ((size_t)l << CAPSHIFT);

    for (unsigned j = tid; j < cnt; j += 256) {
        uint2 r = bk[j];
        int rr = r.x & 31;
        int cc = (r.x >> 5) & 127;
        int plane = (r.x >> 12) & 1;
        float wy1 = (float)(r.x >> 13) * (1.0f / 4095.0f);
        float wx1 = (float)(r.y & 0xFFFF) * (1.0f / 65535.0f);
        float a = (float)(r.y >> 16) * (1.0f / 65535.0f);
        float wy0 = 1.0f - wy1, wx0 = 1.0f - wx1;
        float* Sp = &S[plane][rr][cc];
        atomicAdd(Sp, a * wy0 * wx0);
        atomicAdd(Sp + 1, a * wy0 * wx1);
        atomicAdd(Sp + (TW + 2), a * wy1 * wx0);
        atomicAdd(Sp + (TW + 3), a * wy1 * wx1);
    }
    __syncthreads();

    // focus over ALL own cells: r in [1,TH], c in [1,TW] (final values)
    float a1 = 0.0f, a2 = 0.0f;
    for (int i = tid; i < TH * TW; i += 256) {
        int r = 1 + i / TW;
        int c = 1 + i - (i / TW) * TW;
        float ps = S[0][r][c], ns = S[1][r][c];
        a1 += ps * ps + ns * ns;
        a2 += (ps > 0.0f || ns > 0.0f) ? 1.0f : 0.0f;
    }

    float r1 = block_reduce_256(a1, smem);
    float r2 = block_reduce_256(a2, smem);
    if (tid == 0) {
        atomicAdd(&acc[b], r1);
        atomicAdd(&acc[32 + b], r2);
        __threadfence();
        is_last = (atomicAdd(ticket, 1u) == NT - 1) ? 1u : 0u;
    }
    __syncthreads();
    if (tid == 0 && is_last) {
        float loss = 0.0f;
        for (int bb = 0; bb < BB; ++bb) loss += acc[bb] / (acc[32 + bb] + 1e-9f);
        for (int r = 4; r < 20; ++r) loss += acc[r];
        float tl = 0.0f;
        for (int r = 20; r < 32; ++r) tl += acc[r] / (acc[32 + r] + 1e-9f);
        loss += tl / (float)(PPP - 1);
        out[0] = loss;
    }
}

extern "C" void kernel_launch(void* const* d_in, const int* in_sizes, int n_in,
                              void* d_out, int out_size, void* d_ws, size_t ws_size,
                              hipStream_t stream) {
    const float* ev = (const float*)d_in[0];    // (B,N,2)
    const float* pol = (const float*)d_in[1];   // (B,4N,2)
    const float* ts = (const float*)d_in[2];    // (B,4N,1)
    const float* flow = (const float*)d_in[3];  // (B,P,2,H,W)
    float* out = (float*)d_out;
    float* ws = (float*)d_ws;

    float* acc = ws;                              // [0,64)
    unsigned* ticket = (unsigned*)(ws + 64);      // [64,65)
    unsigned* gcnt = (unsigned*)(ws + 68);        // [68,708)
    uint2* bucket = (uint2*)(ws + 768);           // 8B records, aligned base

    hipMemsetAsync(ws, 0, 3072, stream);  // acc + ticket + gcnt (+pad)

    ka_kernel<<<NTEMP + NSPAT + NBIN, 256, 0, stream>>>(ev, pol, ts, bucket, gcnt, flow, acc);
    kb_kernel<<<NT, 256, 0, stream>>>(bucket, gcnt, acc, ticket, out);
}

// Round 13
// 107.331 us; speedup vs baseline: 1.1866x; 1.1866x over previous
//
#include <hip/hip_runtime.h>

#define HH 480
#define WW 640
#define BB 4
#define PPP 4
#define NN 262144
#define HWPX (HH * WW)

// scatter tiling: 24x80 tiles, 20 rows x 8 cols per batch
#define TH 24
#define TW 80
#define TXN 8                // tiles per row
#define TYN 20               // tiles per col
#define TPB 160              // tiles per batch (20x8)
#define NT (BB * TPB)        // 640 tiles total
#define CAP 2048             // bucket capacity (mean ~1728 incl dups, >7 sigma)
#define CAPSHIFT 11

#define NTEMP 1800           // temporal units: 12 pairs x 150
#define NSPAT 2400           // spatial units: 16 planes x 150
#define NBIN 1024            // bin blocks

__device__ __forceinline__ float charb6(float a) { return sqrtf(a * a + 1e-6f); }

// ---------------- block reduce helper (256 threads) ----------------
__device__ __forceinline__ float block_reduce_256(float v, float* smem) {
#pragma unroll
    for (int off = 32; off > 0; off >>= 1) v += __shfl_down(v, off, 64);
    int lane = threadIdx.x & 63;
    int wid = threadIdx.x >> 6;
    if (lane == 0) smem[wid] = v;
    __syncthreads();
    float r = 0.0f;
    if (threadIdx.x == 0) r = smem[0] + smem[1] + smem[2] + smem[3];
    __syncthreads();
    return r;  // valid only on thread 0
}

// ---------------- Spatial work unit: 2048 px of one plane ----------------
__device__ void spat_work(int s, const float* __restrict__ flow,
                          float* __restrict__ acc, float* smem) {
    int tid = threadIdx.x;
    int plane = s / 150;
    int rem = s - plane * 150;

    const float* fx = flow + (size_t)(plane * 2) * HWPX;
    const float* fy = fx + HWPX;

    const float wdx = 1.0f / ((float)HH * (float)(WW - 1) * (float)PPP * 4.0f);
    const float wdy = 1.0f / ((float)(HH - 1) * (float)WW * (float)PPP * 4.0f);
    const float wdd = 1.0f / ((float)(HH - 1) * (float)(WW - 1) * (float)PPP * 4.0f);

    float a_sp = 0.0f;

#pragma unroll
    for (int q = 0; q < 2; ++q) {
        int off = rem * 2048 + q * 1024 + tid * 4;
        int h = off / WW;
        int c = off - h * WW;

        float mhe = (h < HH - 1) ? 1.0f : 0.0f;
        int ib = (h < HH - 1) ? off + WW : off;
        int ir = (c + 4 < WW) ? off + 4 : off + 3;
        int ibr = (c + 4 < WW) ? ib + 4 : ib + 3;

        float4 fxv = *(const float4*)(fx + off);
        float4 fyv = *(const float4*)(fy + off);
        float4 fxb = *(const float4*)(fx + ib);
        float4 fyb = *(const float4*)(fy + ib);
        float X[5] = {fxv.x, fxv.y, fxv.z, fxv.w, fx[ir]};
        float Y[5] = {fyv.x, fyv.y, fyv.z, fyv.w, fy[ir]};
        float XB[5] = {fxb.x, fxb.y, fxb.z, fxb.w, fx[ibr]};
        float YB[5] = {fyb.x, fyb.y, fyb.z, fyb.w, fy[ibr]};

#pragma unroll
        for (int k = 0; k < 4; ++k) {
            float mwe = (c + k < WW - 1) ? 1.0f : 0.0f;
            a_sp += mwe * wdx * (charb6(X[k] - X[k + 1]) + charb6(Y[k] - Y[k + 1]))
                  + mhe * wdy * (charb6(X[k] - XB[k]) + charb6(Y[k] - YB[k]))
                  + mhe * mwe * wdd * (charb6(X[k] - XB[k + 1]) + charb6(Y[k] - YB[k + 1])
                                     + charb6(XB[k] - X[k + 1]) + charb6(YB[k] - Y[k + 1]));
        }
    }

    float r_sp = block_reduce_256(a_sp, smem);
    if (tid == 0) atomicAdd(&acc[4 + plane], r_sp);
}

// ---------------- Temporal work unit: 2048 px of one plane-pair -----------
__device__ void temp_work(int u, const float* __restrict__ flow,
                          float* __restrict__ acc, float* smem) {
    int tid = threadIdx.x;
    int pair = u / 150;        // 0..11
    int rem = u - pair * 150;
    int bb = pair / 3, pp = pair - bb * 3;
    int cp = bb * 4 + pp;      // cur plane id
    const float* fxc = flow + (size_t)(cp * 2) * HWPX;
    const float* fyc = fxc + HWPX;
    const float* fxn = fxc + 2 * HWPX;
    const float* fyn = fyc + 2 * HWPX;

    float a_dt = 0.0f, a_m = 0.0f;

#pragma unroll
    for (int q = 0; q < 2; ++q) {
        int off = rem * 2048 + q * 1024 + tid * 4;
        int h = off / WW;
        int c = off - h * WW;

        float4 xv = *(const float4*)(fxc + off);
        float4 yv = *(const float4*)(fyc + off);
        float X[4] = {xv.x, xv.y, xv.z, xv.w};
        float Y[4] = {yv.x, yv.y, yv.z, yv.w};

        float msk[4], w00[4], w01[4], w10[4], w11[4];
        int aA[4], aB[4], sel[4];
#pragma unroll
        for (int k = 0; k < 4; ++k) {
            float wy = (float)h + Y[k];
            float wx = (float)(c + k) + X[k];
            msk[k] = (wy >= 0.0f && wy <= (float)(HH - 1) &&
                      wx >= 0.0f && wx <= (float)(WW - 1)) ? 1.0f : 0.0f;
            float y0f = floorf(wy), x0f = floorf(wx);
            float fy1 = wy - y0f, fx1 = wx - x0f;
            float fy0 = 1.0f - fy1, fx0 = 1.0f - fx1;
            w00[k] = fy0 * fx0; w01[k] = fy0 * fx1;
            w10[k] = fy1 * fx0; w11[k] = fy1 * fx1;
            int y0 = (int)fminf(fmaxf(y0f, 0.0f), (float)(HH - 1));
            int y1 = (int)fminf(fmaxf(y0f + 1.0f, 0.0f), (float)(HH - 1));
            int x0 = (int)fminf(fmaxf(x0f, 0.0f), (float)(WW - 1));
            int xl = min(x0, WW - 2);
            sel[k] = x0 - xl;
            aA[k] = y0 * WW + xl;
            aB[k] = y1 * WW + xl;
        }
        float2 A[4], B[4], C[4], D[4];
#pragma unroll
        for (int k = 0; k < 4; ++k) {
            __builtin_memcpy(&A[k], fyn + aA[k], 8);
            __builtin_memcpy(&B[k], fyn + aB[k], 8);
        }
#pragma unroll
        for (int k = 0; k < 4; ++k) {
            __builtin_memcpy(&C[k], fxn + aA[k], 8);
            __builtin_memcpy(&D[k], fxn + aB[k], 8);
        }
#pragma unroll
        for (int k = 0; k < 4; ++k) {
            float a0 = sel[k] ? A[k].y : A[k].x;
            float b0 = sel[k] ? B[k].y : B[k].x;
            float c0 = sel[k] ? C[k].y : C[k].x;
            float d0 = sel[k] ? D[k].y : D[k].x;
            float wfy = w00[k] * a0 + w01[k] * A[k].y + w10[k] * b0 + w11[k] * B[k].y;
            float wfx = w00[k] * c0 + w01[k] * C[k].y + w10[k] * d0 + w11[k] * D[k].y;
            float dy = Y[k] - wfy, dx = X[k] - wfx;
            a_dt += msk[k] * (sqrtf(dy * dy + 1e-9f) + sqrtf(dx * dx + 1e-9f));
            a_m += msk[k];
        }
    }

    float r_dt = block_reduce_256(a_dt, smem);
    float r_m = block_reduce_256(a_m, smem);
    if (tid == 0) {
        atomicAdd(&acc[20 + pair], r_dt);
        atomicAdd(&acc[52 + pair], r_m);
    }
}

// ---------------- K_A: temp || spat || bin (all independent) ---------------
// Bucket record (8B): w0 = r(5) | c<<5(7) | plane<<12(1) | qwy<<13(12)
//                     w1 = qwx(16) | qa<<16(16)
// r = ly+1 in [0,24], c = lx+1 in [0,80] (0 means "from up/left neighbor").
// Boundary-crossing events get DUPLICATE records in neighbor tiles, ranked
// via the SAME LDS histogram (dup targets are in-batch) — no global atomics.
__global__ __launch_bounds__(256, 8) void ka_kernel(
        const float* __restrict__ ev, const float* __restrict__ pol,
        const float* __restrict__ ts, uint2* __restrict__ bucket,
        unsigned* __restrict__ gcnt, const float* __restrict__ flow,
        float* __restrict__ acc) {
    __shared__ unsigned ubuf[2 * TPB];
    __shared__ float smem[4];
    int tid = threadIdx.x;

    if (blockIdx.x < NTEMP) {
        int i = blockIdx.x;
        int u = (i & 7) * (NTEMP / 8) + (i >> 3);     // XCD-chunked, bijective
        temp_work(u, flow, acc, smem);
    } else if (blockIdx.x < NTEMP + NSPAT) {
        int i = blockIdx.x - NTEMP;
        int s = (i & 7) * (NSPAT / 8) + (i >> 3);
        spat_work(s, flow, acc, smem);
    } else {
        // ---- bin: counting-sort events into per-tile buckets ----
        unsigned* hist = ubuf;
        unsigned* basebuf = ubuf + TPB;
        if (tid < TPB) hist[tid] = 0;
        __syncthreads();

        int start = (blockIdx.x - (NTEMP + NSPAT)) * 1024;
        int b = start >> 18;
        const float2* ev2 = (const float2*)ev;

        unsigned p0[4], p1[4];
        int tt[4];
        unsigned rr[4], rd1[4], rd2[4], rd3[4];
        unsigned dupm[4];  // bit0: right, bit1: down
#pragma unroll
        for (int k = 0; k < 4; ++k) {
            int gidx = start + tid + k * 256;
            int n = gidx & (NN - 1);
            float2 e = ev2[gidx];
            float y = e.x, x = e.y;
            int iy = (int)floorf(y), ix = (int)floorf(x);
            int ty = iy / TH, txx = ix / TW;
            int t = ty * TXN + txx;
            int ly = iy - ty * TH, lx = ix - txx * TW;
            float wy1 = y - (float)iy, wx1 = x - (float)ix;
            float pm0 = pol[((size_t)b * 4 * NN + n) * 2];
            float tsv = ts[(size_t)b * 4 * NN + n];
            float nt = 1.0f - fabsf(1.0f - tsv);
            float a = nt * nt;
            unsigned qwy = (unsigned)(wy1 * 4095.0f + 0.5f);
            unsigned qwx = (unsigned)(wx1 * 65535.0f + 0.5f);
            unsigned qa  = (unsigned)(a * 65535.0f + 0.5f);
            unsigned plane = (pm0 > 0.5f) ? 0u : 1u;
            p0[k] = (unsigned)(ly + 1) | ((unsigned)(lx + 1) << 5) | (plane << 12) | (qwy << 13);
            p1[k] = qwx | (qa << 16);
            tt[k] = t;
            dupm[k] = ((lx == TW - 1 && txx < TXN - 1) ? 1u : 0u) |
                      ((ly == TH - 1 && ty < TYN - 1) ? 2u : 0u);
            rr[k] = atomicAdd(&hist[t], 1u);
            if (dupm[k] & 1u) rd1[k] = atomicAdd(&hist[t + 1], 1u);
            if (dupm[k] & 2u) rd2[k] = atomicAdd(&hist[t + TXN], 1u);
            if (dupm[k] == 3u) rd3[k] = atomicAdd(&hist[t + TXN + 1], 1u);
        }
        __syncthreads();
        if (tid < TPB) basebuf[tid] = atomicAdd(&gcnt[b * TPB + tid], hist[tid]);
        __syncthreads();

#pragma unroll
        for (int k = 0; k < 4; ++k) {
            unsigned slot = basebuf[tt[k]] + rr[k];
            if (slot < CAP)
                bucket[((size_t)(b * TPB + tt[k]) << CAPSHIFT) + slot] =
                    make_uint2(p0[k], p1[k]);
            if (dupm[k]) {
                unsigned base0 = p0[k] & 0xFFFFE000u;  // plane|qwy bits
                unsigned r5 = p0[k] & 31u;
                unsigned c7 = (p0[k] >> 5) & 127u;
                if (dupm[k] & 1u) {  // right neighbor: c -> 0
                    int dst = tt[k] + 1;
                    unsigned s2 = basebuf[dst] + rd1[k];
                    if (s2 < CAP)
                        bucket[((size_t)(b * TPB + dst) << CAPSHIFT) + s2] =
                            make_uint2(base0 | r5, p1[k]);
                }
                if (dupm[k] & 2u) {  // down neighbor: r -> 0
                    int dst = tt[k] + TXN;
                    unsigned s2 = basebuf[dst] + rd2[k];
                    if (s2 < CAP)
                        bucket[((size_t)(b * TPB + dst) << CAPSHIFT) + s2] =
                            make_uint2(base0 | (c7 << 5), p1[k]);
                }
                if (dupm[k] == 3u) {  // diag neighbor: r,c -> 0
                    int dst = tt[k] + TXN + 1;
                    unsigned s2 = basebuf[dst] + rd3[k];
                    if (s2 < CAP)
                        bucket[((size_t)(b * TPB + dst) << CAPSHIFT) + s2] =
                            make_uint2(base0, p1[k]);
                }
            }
        }
    }
}

// ---------------- K_B: tile accumulate + full in-tile focus + finalize -----
__global__ __launch_bounds__(256, 8) void kb_kernel(
        const uint2* __restrict__ bucket, const unsigned* __restrict__ gcnt,
        float* __restrict__ acc, unsigned* __restrict__ ticket,
        float* __restrict__ out) {
    __shared__ float S[2][TH + 2][TW + 2];   // +1 ring on all sides
    __shared__ float smem[4];
    __shared__ unsigned is_last;
    int tid = threadIdx.x;
    int l = blockIdx.x;
    int b = l / TPB;

    for (int i = tid; i < 2 * (TH + 2) * (TW + 2); i += 256) ((float*)S)[i] = 0.0f;
    __syncthreads();

    unsigned cnt = gcnt[l];
    if (cnt > CAP) cnt = CAP;
    const uint2* bk = bucket + ((size_t)l << CAPSHIFT);

    for (unsigned j = tid; j < cnt; j += 256) {
        uint2 r = bk[j];
        int rr = r.x & 31;
        int cc = (r.x >> 5) & 127;
        int plane = (r.x >> 12) & 1;
        float wy1 = (float)(r.x >> 13) * (1.0f / 4095.0f);
        float wx1 = (float)(r.y & 0xFFFF) * (1.0f / 65535.0f);
        float a = (float)(r.y >> 16) * (1.0f / 65535.0f);
        float wy0 = 1.0f - wy1, wx0 = 1.0f - wx1;
        float* Sp = &S[plane][rr][cc];
        atomicAdd(Sp, a * wy0 * wx0);
        atomicAdd(Sp + 1, a * wy0 * wx1);
        atomicAdd(Sp + (TW + 2), a * wy1 * wx0);
        atomicAdd(Sp + (TW + 3), a * wy1 * wx1);
    }
    __syncthreads();

    // focus over ALL own cells: r in [1,TH], c in [1,TW] (final values)
    float a1 = 0.0f, a2 = 0.0f;
    for (int i = tid; i < TH * TW; i += 256) {
        int r = 1 + i / TW;
        int c = 1 + i - (i / TW) * TW;
        float ps = S[0][r][c], ns = S[1][r][c];
        a1 += ps * ps + ns * ns;
        a2 += (ps > 0.0f || ns > 0.0f) ? 1.0f : 0.0f;
    }

    float r1 = block_reduce_256(a1, smem);
    float r2 = block_reduce_256(a2, smem);
    if (tid == 0) {
        atomicAdd(&acc[b], r1);
        atomicAdd(&acc[32 + b], r2);
        __threadfence();
        is_last = (atomicAdd(ticket, 1u) == NT - 1) ? 1u : 0u;
    }
    __syncthreads();
    if (tid == 0 && is_last) {
        float loss = 0.0f;
        for (int bb = 0; bb < BB; ++bb) loss += acc[bb] / (acc[32 + bb] + 1e-9f);
        for (int r = 4; r < 20; ++r) loss += acc[r];
        float tl = 0.0f;
        for (int r = 20; r < 32; ++r) tl += acc[r] / (acc[32 + r] + 1e-9f);
        loss += tl / (float)(PPP - 1);
        out[0] = loss;
    }
}

extern "C" void kernel_launch(void* const* d_in, const int* in_sizes, int n_in,
                              void* d_out, int out_size, void* d_ws, size_t ws_size,
                              hipStream_t stream) {
    const float* ev = (const float*)d_in[0];    // (B,N,2)
    const float* pol = (const float*)d_in[1];   // (B,4N,2)
    const float* ts = (const float*)d_in[2];    // (B,4N,1)
    const float* flow = (const float*)d_in[3];  // (B,P,2,H,W)
    float* out = (float*)d_out;
    float* ws = (float*)d_ws;

    float* acc = ws;                              // [0,64)
    unsigned* ticket = (unsigned*)(ws + 64);      // [64,65)
    unsigned* gcnt = (unsigned*)(ws + 68);        // [68,708)
    uint2* bucket = (uint2*)(ws + 768);           // 8B records, aligned base

    hipMemsetAsync(ws, 0, 3072, stream);  // acc + ticket + gcnt (+pad)

    ka_kernel<<<NTEMP + NSPAT + NBIN, 256, 0, stream>>>(ev, pol, ts, bucket, gcnt, flow, acc);
    kb_kernel<<<NT, 256, 0, stream>>>(bucket, gcnt, acc, ticket, out);
}